// Round 11
// baseline (111.471 us; speedup 1.0000x reference)
//
#include <hip/hip_runtime.h>
#include <hip/hip_bf16.h>

#define TT 256   // sequence length
#define CE 384   // embed
#define HD 64    // head size

typedef __attribute__((ext_vector_type(8))) short short8v;
typedef __attribute__((ext_vector_type(4))) float float4v;
typedef __attribute__((ext_vector_type(4))) unsigned int uint4v;
typedef __attribute__((ext_vector_type(4))) unsigned short ushort4v;

#define SCALE 0.05103103630798287f  // 384^-0.5 (reference scales by C, not H)

__device__ __forceinline__ unsigned short f2bf(float f) {
    union { __hip_bfloat16 b; unsigned short u; } cv;
    cv.b = __float2bfloat16(f);   // RNE; pairs fuse to v_cvt_pk_bf16_f32
    return cv.u;
}
__device__ __forceinline__ unsigned int pk2(float a, float b) {
    return (unsigned int)f2bf(a) | ((unsigned int)f2bf(b) << 16);
}

// Swizzled LDS addressing (16B-chunk XOR of row bits -> conflict-free frags)
__device__ __forceinline__ int adr8(int row, int col) {   // rows of 64 bf16 (128 B)
    return row * 128 + ((((col >> 3) ^ (row & 7)) & 7) << 4) + ((col & 7) << 1);
}
__device__ __forceinline__ int adr16(int row, int col) {  // rows of 128 bf16 (256 B)
    return row * 256 + ((((col >> 3) ^ (row & 15)) & 15) << 4) + ((col & 7) << 1);
}
__device__ __forceinline__ int adr32(int row, int col) {  // rows of 256 bf16 (512 B)
    return row * 512 + ((((col >> 3) ^ (row & 31)) & 31) << 4) + ((col & 7) << 1);
}

// raw barrier: drain LDS ops only; global loads stay in flight (r5-proven form)
#define BAR() do {                                            \
    asm volatile("s_waitcnt lgkmcnt(0)" ::: "memory");        \
    __builtin_amdgcn_s_barrier();                             \
    __builtin_amdgcn_sched_barrier(0);                        \
} while (0)

// ---------------- kernel 0: weight transpose + bf16 convert -----------------
__global__ void wprep(const float* __restrict__ Wk, const float* __restrict__ Wq,
                      const float* __restrict__ Wv, unsigned short* __restrict__ Wt) {
    int idx = blockIdx.x * 256 + threadIdx.x;
    if (idx >= 3 * HD * CE) return;
    int w = idx / (HD * CE);
    int rem = idx - w * (HD * CE);
    int h = rem / CE;
    int c = rem - h * CE;
    const float* W = (w == 0) ? Wk : (w == 1) ? Wq : Wv;
    Wt[idx] = f2bf(W[c * HD + h]);
}

// ---------------- fused kernel: QKV + attention, one batch per block --------
// 1024 threads (16 waves = 4 waves/SIMD), grid 512, 160 KiB LDS (1 block/CU):
//   Vts @ 0      : 32 KiB  V^T [64][256] bf16 (adr32)   -- live all phase 2
//   Qs  @ 32768  : 32 KiB  Q   [256][64] bf16 (adr8)    -- live thru QK^T
//   Ks  @ 65536  : 32 KiB  K   [256][64] bf16 (adr8)    -- live thru QK^T
//   Xs  @ 98304  : 32 KiB  phase-1 X staging (adr8)     \ dead after phase 1
//   Ws  @ 131072 : 24 KiB  phase-1 W staging (adr8)     /
//   Wts @ 98304  : 64 KiB  weights [256][128] bf16 (adr16), per s-block;
//                  smx (float2[2][128], 2 KiB) lives at its head transiently
//                  between QK^T and the Wts write (barrier-separated).
// VGPR cap 128 via __launch_bounds__(1024) -- NOT (1024,N)! (r5 ERRATA:
// 2nd arg is waves/SIMD; 4 meant 64 VGPR -> spill.)
__global__ __launch_bounds__(1024)
void fused(const float* __restrict__ X, const unsigned short* __restrict__ Wt,
           float* __restrict__ out) {
    extern __shared__ char lds[];
    char* Vts = lds;
    char* Qs  = lds + 32768;
    char* Ks  = lds + 65536;
    char* Xs  = lds + 98304;
    char* Ws  = lds + 131072;
    char* Wts = lds + 98304;
    float2* smx = (float2*)Wts;   // [2][128]

    const int tid = threadIdx.x;
    const int w = tid >> 6, l = tid & 63;
    const int l15 = l & 15, lq = l >> 4;
    const int tg = w & 7, nh = w >> 3;   // phase-1: t-rows tg*32..+32, n-cols nh*96..+96
    const int sw = w & 7, th = w >> 3;   // phase-2: s-rows sw*16..+16, t-half th

    const int b = blockIdx.x;
    const float* Xb = X + (long)b * TT * CE;

    // staging slots: X 2048 16B-chunks / 1024 thr = 2; W 1536 / 1024 = 1.5
    const int xt0 = tid >> 3,         xk0 = tid & 7;
    const int xt1 = 128 + (tid >> 3), xk1 = tid & 7;
    const int wn0 = tid >> 3,         wk0 = tid & 7;
    const int wn1 = 128 + (tid >> 3), wk1 = tid & 7;
    const bool wp = (tid < 512);

    // named 2-deep register double-buffer (rule #20)
    float4 xrA[2][2]; uint4v wrA[2];
    float4 xrB[2][2]; uint4v wrB[2];

    auto issueA = [&](int kk) {
        const float* s0 = Xb + xt0 * CE + kk + xk0 * 8;
        xrA[0][0] = *(const float4*)s0;  xrA[0][1] = *(const float4*)(s0 + 4);
        const float* s1 = Xb + xt1 * CE + kk + xk1 * 8;
        xrA[1][0] = *(const float4*)s1;  xrA[1][1] = *(const float4*)(s1 + 4);
        wrA[0] = *(const uint4v*)(Wt + wn0 * CE + kk + wk0 * 8);
        if (wp) wrA[1] = *(const uint4v*)(Wt + wn1 * CE + kk + wk1 * 8);
    };
    auto issueB = [&](int kk) {
        const float* s0 = Xb + xt0 * CE + kk + xk0 * 8;
        xrB[0][0] = *(const float4*)s0;  xrB[0][1] = *(const float4*)(s0 + 4);
        const float* s1 = Xb + xt1 * CE + kk + xk1 * 8;
        xrB[1][0] = *(const float4*)s1;  xrB[1][1] = *(const float4*)(s1 + 4);
        wrB[0] = *(const uint4v*)(Wt + wn0 * CE + kk + wk0 * 8);
        if (wp) wrB[1] = *(const uint4v*)(Wt + wn1 * CE + kk + wk1 * 8);
    };
    auto storeA = [&]() {
        uint4v p0 = {pk2(xrA[0][0].x, xrA[0][0].y), pk2(xrA[0][0].z, xrA[0][0].w),
                     pk2(xrA[0][1].x, xrA[0][1].y), pk2(xrA[0][1].z, xrA[0][1].w)};
        *(uint4v*)(Xs + xt0 * 128 + (((xk0 ^ (xt0 & 7)) & 7) << 4)) = p0;
        uint4v p1 = {pk2(xrA[1][0].x, xrA[1][0].y), pk2(xrA[1][0].z, xrA[1][0].w),
                     pk2(xrA[1][1].x, xrA[1][1].y), pk2(xrA[1][1].z, xrA[1][1].w)};
        *(uint4v*)(Xs + xt1 * 128 + (((xk1 ^ (xt1 & 7)) & 7) << 4)) = p1;
        *(uint4v*)(Ws + wn0 * 128 + (((wk0 ^ (wn0 & 7)) & 7) << 4)) = wrA[0];
        if (wp) *(uint4v*)(Ws + wn1 * 128 + (((wk1 ^ (wn1 & 7)) & 7) << 4)) = wrA[1];
    };
    auto storeB = [&]() {
        uint4v p0 = {pk2(xrB[0][0].x, xrB[0][0].y), pk2(xrB[0][0].z, xrB[0][0].w),
                     pk2(xrB[0][1].x, xrB[0][1].y), pk2(xrB[0][1].z, xrB[0][1].w)};
        *(uint4v*)(Xs + xt0 * 128 + (((xk0 ^ (xt0 & 7)) & 7) << 4)) = p0;
        uint4v p1 = {pk2(xrB[1][0].x, xrB[1][0].y), pk2(xrB[1][0].z, xrB[1][0].w),
                     pk2(xrB[1][1].x, xrB[1][1].y), pk2(xrB[1][1].z, xrB[1][1].w)};
        *(uint4v*)(Xs + xt1 * 128 + (((xk1 ^ (xt1 & 7)) & 7) << 4)) = p1;
        *(uint4v*)(Ws + wn0 * 128 + (((wk0 ^ (wn0 & 7)) & 7) << 4)) = wrB[0];
        if (wp) *(uint4v*)(Ws + wn1 * 128 + (((wk1 ^ (wn1 & 7)) & 7) << 4)) = wrB[1];
    };

    const float4v fzero = {0.f, 0.f, 0.f, 0.f};
    float4v acc[2][6];
    #pragma unroll
    for (int i = 0; i < 2; ++i)
        #pragma unroll
        for (int j = 0; j < 6; ++j) acc[i][j] = fzero;

    auto mfma_phase = [&]() {
        #pragma unroll
        for (int ks = 0; ks < 2; ++ks) {
            short8v a0 = *(const short8v*)(Xs + adr8(tg * 32 + l15,      ks * 32 + lq * 8));
            short8v a1 = *(const short8v*)(Xs + adr8(tg * 32 + 16 + l15, ks * 32 + lq * 8));
            #pragma unroll
            for (int nt = 0; nt < 6; ++nt) {
                short8v bb = *(const short8v*)(Ws + adr8(nh * 96 + nt * 16 + l15, ks * 32 + lq * 8));
                acc[0][nt] = __builtin_amdgcn_mfma_f32_16x16x32_bf16(a0, bb, acc[0][nt], 0, 0, 0);
                acc[1][nt] = __builtin_amdgcn_mfma_f32_16x16x32_bf16(a1, bb, acc[1][nt], 0, 0, 0);
            }
        }
    };

    // ---------------- phase 1: QKV = X @ [Wk|Wq|Wv] -------------------------
    issueA(0);
    issueB(64);
    #pragma unroll
    for (int kc2 = 0; kc2 < 3; ++kc2) {
        storeA();                              // counted vmcnt waits A-regs only
        if (kc2 < 2) issueA((2 * kc2 + 2) * 64);
        BAR();                                 // staging visible; B-loads in flight
        mfma_phase();
        BAR();                                 // frag reads done; buffers reusable
        storeB();
        if (kc2 < 2) issueB((2 * kc2 + 3) * 64);
        BAR();
        mfma_phase();
        BAR();
    }

    // epilogue: K -> Ks, Q -> Qs (adr8); V -> Vts transposed [h][t] (adr32)
    #pragma unroll
    for (int rt = 0; rt < 2; ++rt) {
        const int t0 = tg * 32 + rt * 16 + lq * 4;
        #pragma unroll
        for (int nt = 0; nt < 6; ++nt) {
            const int n = nh * 96 + nt * 16 + l15;
            if (n < 64) {              // K
                #pragma unroll
                for (int r = 0; r < 4; ++r)
                    *(unsigned short*)(Ks + adr8(t0 + r, n)) = f2bf(acc[rt][nt][r]);
            } else if (n < 128) {      // Q
                const int h = n - 64;
                #pragma unroll
                for (int r = 0; r < 4; ++r)
                    *(unsigned short*)(Qs + adr8(t0 + r, h)) = f2bf(acc[rt][nt][r]);
            } else {                   // V -> [h][t]
                const int h = n - 128;
                ushort4v pv;
                pv[0] = f2bf(acc[rt][nt][0]);
                pv[1] = f2bf(acc[rt][nt][1]);
                pv[2] = f2bf(acc[rt][nt][2]);
                pv[3] = f2bf(acc[rt][nt][3]);
                *(ushort4v*)(Vts + adr32(h, t0)) = pv;
            }
        }
    }
    BAR();   // K/Q/V visible; phase-1 staging region now dead

    // ---------------- phase 2: attention, 2 s-blocks of 128 ------------------
    float4v o[4];
    #pragma unroll
    for (int ht = 0; ht < 4; ++ht) o[ht] = fzero;

    #pragma unroll
    for (int sb = 0; sb < 2; ++sb) {
        const int s0 = sb * 128;

        // Z = K Q^T : wave (sw,th) -> s-rows s0+sw*16..+16, t-half th*128..+128
        float4v z[8];
        #pragma unroll
        for (int tt = 0; tt < 8; ++tt) z[tt] = fzero;
        #pragma unroll
        for (int ks = 0; ks < 2; ++ks) {
            short8v ak = *(const short8v*)(Ks + adr8(s0 + sw * 16 + l15, ks * 32 + lq * 8));
            #pragma unroll
            for (int tt = 0; tt < 8; ++tt) {
                short8v bq = *(const short8v*)(Qs + adr8(th * 128 + tt * 16 + l15, ks * 32 + lq * 8));
                z[tt] = __builtin_amdgcn_mfma_f32_16x16x32_bf16(ak, bq, z[tt], 0, 0, 0);
            }
        }

        // local softmax partials over this wave's t-half (query axis!)
        float pm[4], ps4[4], fac[4];
        #pragma unroll
        for (int r = 0; r < 4; ++r) {
            const int s = s0 + sw * 16 + lq * 4 + r;
            float mm = -1e30f;
            #pragma unroll
            for (int tt = 0; tt < 8; ++tt) {
                int t = th * 128 + tt * 16 + l15;
                float v = (t >= s) ? z[tt][r] * SCALE : -1e30f;  // causal: keep t >= s
                z[tt][r] = v;
                mm = fmaxf(mm, v);
            }
            mm = fmaxf(mm, __shfl_xor(mm, 1));
            mm = fmaxf(mm, __shfl_xor(mm, 2));
            mm = fmaxf(mm, __shfl_xor(mm, 4));
            mm = fmaxf(mm, __shfl_xor(mm, 8));
            float ps = 0.f;
            #pragma unroll
            for (int tt = 0; tt < 8; ++tt) {
                float p = (z[tt][r] > -1e29f) ? __expf(z[tt][r] - mm) : 0.f;
                z[tt][r] = p;
                ps += p;
            }
            ps += __shfl_xor(ps, 1);
            ps += __shfl_xor(ps, 2);
            ps += __shfl_xor(ps, 4);
            ps += __shfl_xor(ps, 8);
            pm[r] = mm;
            ps4[r] = ps;
        }
        BAR();   // sb=0: phase-1 reads of Wts region done; sb=1: prev PV Wts reads done

        // publish (max,sum) partials into the head of the Wts buffer
        #pragma unroll
        for (int r = 0; r < 4; ++r)
            if (l15 == 0) smx[th * 128 + sw * 16 + lq * 4 + r] = make_float2(pm[r], ps4[r]);
        BAR();   // smx visible

        // merge the two t-halves -> per-row normalize factor
        #pragma unroll
        for (int r = 0; r < 4; ++r) {
            const int row = sw * 16 + lq * 4 + r;
            float2 h0 = smx[row];
            float2 h1 = smx[128 + row];
            float m = fmaxf(h0.x, h1.x);
            float denom = h0.y * __expf(h0.x - m) + h1.y * __expf(h1.x - m);
            fac[r] = __expf(pm[r] - m) / denom;
        }
        BAR();   // smx reads done -> Wts writes may overwrite it

        // normalized weights -> Wts[t][s_local] (bf16, adr16)
        #pragma unroll
        for (int tt = 0; tt < 8; ++tt) {
            const int t = th * 128 + tt * 16 + l15;
            const int col = sw * 16 + lq * 4;
            ushort4v pw;
            pw[0] = f2bf(z[tt][0] * fac[0]);
            pw[1] = f2bf(z[tt][1] * fac[1]);
            pw[2] = f2bf(z[tt][2] * fac[2]);
            pw[3] = f2bf(z[tt][3] * fac[3]);
            *(ushort4v*)(Wts + adr16(t, col)) = pw;
        }
        BAR();   // Wts visible

        // O += W V : wave owns t-rows w*16..+16, all 64 h, k = 128 s-cols
        #pragma unroll
        for (int ks = 0; ks < 4; ++ks) {
            short8v aw = *(const short8v*)(Wts + adr16(w * 16 + l15, ks * 32 + lq * 8));
            #pragma unroll
            for (int ht = 0; ht < 4; ++ht) {
                short8v bv = *(const short8v*)(Vts + adr32(ht * 16 + l15, s0 + ks * 32 + lq * 8));
                o[ht] = __builtin_amdgcn_mfma_f32_16x16x32_bf16(aw, bv, o[ht], 0, 0, 0);
            }
        }
    }

    // store O (f32; 16 lanes write 64B contiguous per (t,ht))
    float* ob = out + (long)b * TT * HD;
    #pragma unroll
    for (int ht = 0; ht < 4; ++ht)
        #pragma unroll
        for (int r = 0; r < 4; ++r)
            ob[(w * 16 + lq * 4 + r) * HD + ht * 16 + l15] = o[ht][r];
}

// ---------------------------------------------------------------------------
extern "C" void kernel_launch(void* const* d_in, const int* in_sizes, int n_in,
                              void* d_out, int out_size, void* d_ws, size_t ws_size,
                              hipStream_t stream) {
    const float* X  = (const float*)d_in[0];
    const float* Wk = (const float*)d_in[1];
    const float* Wq = (const float*)d_in[2];
    const float* Wv = (const float*)d_in[3];
    float* out = (float*)d_out;

    unsigned short* Wt = (unsigned short*)d_ws;   // 3*64*384 bf16 = 147456 B

    (void)hipFuncSetAttribute(reinterpret_cast<const void*>(fused),
                              hipFuncAttributeMaxDynamicSharedMemorySize, 163840);

    wprep<<<288, 256, 0, stream>>>(Wk, Wq, Wv, Wt);
    fused<<<512, 1024, 163840, stream>>>(X, Wt, out);
}